// Round 10
// baseline (87.930 us; speedup 1.0000x reference)
//
#include <hip/hip_runtime.h>

#define N_NODES 100000
#define DEG 16
#define N_EDGES (N_NODES * DEG)
#define NT 64                              // nodes per k_edge block
#define NBLK2 ((N_NODES + NT - 1) / NT)    // 1563 edge blocks
#define NBLK_AB 1024                       // k_ab blocks: 4096 waves, 2048 per half
#define NPW 49                             // nodes per wave-pair (2048*49 >= N)

// ---------------------------------------------------------------------------
// Prep: w0T[k][o] = A/B-split transpose of w0:
//   o <  64 : w0[o][k]        (A-part: weight for hidden o, input k)
//   o >= 64 : w0[o-64][64+k]  (B-part: weight for hidden o-64, input 64+k)
// ---------------------------------------------------------------------------
__global__ __launch_bounds__(256) void k_prep(const float* __restrict__ w0,
                                              float* __restrict__ w0T) {
    int id = blockIdx.x * 256 + threadIdx.x;
    if (id < 64 * 128) {
        int k = id >> 7, o = id & 127;
        w0T[k * 128 + o] = (o < 64) ? w0[o * 129 + k]
                                    : w0[(o - 64) * 129 + 64 + k];
    }
}

// ---------------------------------------------------------------------------
// Kernel 1 v8 — ZERO-LDS matvec. Six LDS-staged designs all hit ~40us: the
// common resource was the per-CU LDS read pipe (~23us of ds_read_b128) that
// W+f staging forces. Here: wave = one output half (A|B), lane = output col;
// the lane's W column sits in 64 VGPRs (one-time coalesced load); per node,
// f is wave-uniform (readfirstlane'd pointer -> s_load / L1-broadcast).
// 2 nodes in flight (ILP 2 covers the 4cyc fma dep chain at 2cyc issue).
// Chain per (n,o): k ascending 0..63 fmaf, +b0 after -> AB bit-identical.
// Tail: clamped node ids duplicate work; duplicate stores write identical
// values (same chain, same inputs) -> deterministic.
// ---------------------------------------------------------------------------
__global__ __launch_bounds__(256) void k_ab(const float* __restrict__ feat,
                                            const float* __restrict__ w0T,
                                            const float* __restrict__ b0,
                                            float* __restrict__ AB) {
    const int lane = threadIdx.x & 63;
    const int wid  = threadIdx.x >> 6;
    const int gw   = blockIdx.x * 4 + wid;   // 0..4095
    const int half = gw & 1;                 // 0 = A-outs, 1 = B-outs
    const int wix  = gw >> 1;                // 0..2047
    const int start = wix * NPW;
    if (start >= N_NODES) return;
    const int lim = min(start + NPW, N_NODES);

    // this lane's W column (64 regs): w0T row k is 128 contiguous floats,
    // lanes 0..63 read consecutive addresses -> coalesced 256B per load.
    float wreg[64];
#pragma unroll
    for (int k = 0; k < 64; ++k)
        wreg[k] = w0T[k * 128 + half * 64 + lane];

    const float b0v = (half == 0) ? b0[lane] : 0.f;   // b0 folds into A-half

#define FMA8(ACC, X, Y, KC)                                   \
    ACC = fmaf(X.x, wreg[(KC) * 8 + 0], ACC);                 \
    ACC = fmaf(X.y, wreg[(KC) * 8 + 1], ACC);                 \
    ACC = fmaf(X.z, wreg[(KC) * 8 + 2], ACC);                 \
    ACC = fmaf(X.w, wreg[(KC) * 8 + 3], ACC);                 \
    ACC = fmaf(Y.x, wreg[(KC) * 8 + 4], ACC);                 \
    ACC = fmaf(Y.y, wreg[(KC) * 8 + 5], ACC);                 \
    ACC = fmaf(Y.z, wreg[(KC) * 8 + 6], ACC);                 \
    ACC = fmaf(Y.w, wreg[(KC) * 8 + 7], ACC);

#pragma unroll 1
    for (int nb = start; nb < lim; nb += 2) {
        const int n0u = __builtin_amdgcn_readfirstlane(nb);
        const int n1u = __builtin_amdgcn_readfirstlane((nb + 1 < lim) ? nb + 1 : nb);
        const float* f0 = feat + (size_t)n0u * 64;
        const float* f1 = feat + (size_t)n1u * 64;
        float a0 = 0.f, a1 = 0.f;
#pragma unroll
        for (int kc = 0; kc < 8; ++kc) {
            float4 x0 = *(const float4*)(f0 + kc * 8);
            float4 y0 = *(const float4*)(f0 + kc * 8 + 4);
            float4 x1 = *(const float4*)(f1 + kc * 8);
            float4 y1 = *(const float4*)(f1 + kc * 8 + 4);
            FMA8(a0, x0, y0, kc)
            FMA8(a1, x1, y1, kc)
        }
        AB[(size_t)n0u * 128 + half * 64 + lane] = a0 + b0v;
        AB[(size_t)n1u * 128 + half * 64 + lane] = a1 + b0v;  // dup-safe
    }
#undef FMA8
}

// ---------------------------------------------------------------------------
// Kernel 2 v3 (round-9 verbatim, ~21us): B staged in LDS, A read per-q from
// global (4 lanes share each address -> L1 broadcast). LDS ~22.3 KB.
// ---------------------------------------------------------------------------
__global__ __launch_bounds__(256) void k_edge(const float* __restrict__ AB,
                                              const float* __restrict__ values,
                                              const int* __restrict__ indices,
                                              const float* __restrict__ w0,
                                              const float* __restrict__ w1,
                                              const float* __restrict__ b1,
                                              float* __restrict__ z,
                                              double* __restrict__ partial) {
    __shared__ float b_s[80][68];
    __shared__ float wv_s[64];
    __shared__ float w1_s[64];
    __shared__ double redw[4];
    const int t = threadIdx.x;
    const int n0 = blockIdx.x * NT;
    const int nvalid = min(NT, N_NODES - n0);

    if (t < 64) {
        wv_s[t] = w0[t * 129 + 128];
        w1_s[t] = w1[t];
    }
    for (int idx = t; idx < 1280; idx += 256) {        // B: 80 rows x 16 float4
        int r = idx >> 4, k4 = idx & 15;
        int node = n0 + 1 + r;
        if (node >= N_NODES) node -= N_NODES;
        *(float4*)&b_s[r][k4 * 4] = *(const float4*)(AB + (size_t)node * 128 + 64 + k4 * 4);
    }
    __syncthreads();

    const int row = t >> 2;
    const bool ok = row < nvalid;
    double ss = 0.0;
    if (ok) {
        const float* Ap = AB + (size_t)(n0 + row) * 128;   // L1-broadcast reads
        const int ebase = n0 * 16 + (t << 2);
        int4   c4 = *(const int4*)(indices + N_EDGES + ebase);
        float4 v4 = *(const float4*)(values + ebase);
        int   cols[4] = {c4.x, c4.y, c4.z, c4.w};
        float vv[4]   = {v4.x, v4.y, v4.z, v4.w};
        int   ii[4];
        bool  fb[4];
        bool  anyfb = false;
#pragma unroll
        for (int k = 0; k < 4; ++k) {
            int i = cols[k] - (n0 + 1);
            if (i < 0) i += N_NODES;
            fb[k] = (i >= 80);
            anyfb |= fb[k];
            ii[k] = fb[k] ? 0 : i;
        }
        float acc[4] = {0.f, 0.f, 0.f, 0.f};
#pragma unroll
        for (int q = 0; q < 16; ++q) {
            float4 a4  = *(const float4*)(Ap + q * 4);
            float4 wv4 = *(const float4*)&wv_s[q * 4];
            float4 w14 = *(const float4*)&w1_s[q * 4];
#pragma unroll
            for (int k = 0; k < 4; ++k) {
                float4 b4 = *(const float4*)&b_s[ii[k]][q * 4];
                float t0 = fmaf(wv4.x, vv[k], a4.x + b4.x);
                float t1 = fmaf(wv4.y, vv[k], a4.y + b4.y);
                float t2 = fmaf(wv4.z, vv[k], a4.z + b4.z);
                float t3 = fmaf(wv4.w, vv[k], a4.w + b4.w);
                acc[k] = fmaf(w14.x, fmaxf(t0, 0.f), acc[k]);
                acc[k] = fmaf(w14.y, fmaxf(t1, 0.f), acc[k]);
                acc[k] = fmaf(w14.z, fmaxf(t2, 0.f), acc[k]);
                acc[k] = fmaf(w14.w, fmaxf(t3, 0.f), acc[k]);
            }
        }
        if (anyfb) {            // never taken for this graph; correctness net
#pragma unroll
            for (int k = 0; k < 4; ++k) {
                if (fb[k]) {
                    const float* Bp = AB + (size_t)cols[k] * 128 + 64;
                    float a = 0.f;
                    for (int h = 0; h < 64; ++h) {
                        float th = fmaf(wv_s[h], vv[k], Ap[h] + Bp[h]);
                        a = fmaf(w1_s[h], fmaxf(th, 0.f), a);
                    }
                    acc[k] = a;
                }
            }
        }
        const float b1v = b1[0];
        float4 z4;
        z4.x = acc[0] + b1v; z4.y = acc[1] + b1v;
        z4.z = acc[2] + b1v; z4.w = acc[3] + b1v;
        *(float4*)(z + ebase) = z4;
        ss = (double)z4.x * z4.x + (double)z4.y * z4.y +
             (double)z4.z * z4.z + (double)z4.w * z4.w;
    }
    // deterministic wave shuffle reduce (fp64), then 4 partials -> block sum
#pragma unroll
    for (int off = 32; off > 0; off >>= 1) ss += __shfl_down(ss, off, 64);
    if ((t & 63) == 0) redw[t >> 6] = ss;
    __syncthreads();
    if (t == 0) partial[blockIdx.x] = (redw[0] + redw[1]) + (redw[2] + redw[3]);
}

// ---------------------------------------------------------------------------
// Deterministic fp64 reduction of block partials -> max(||z||, 1e-12)
// ---------------------------------------------------------------------------
__global__ __launch_bounds__(256) void k_norm(const double* __restrict__ partial,
                                              double* __restrict__ nrm) {
    __shared__ double red[256];
    const int t = threadIdx.x;
    double s = 0.0;
    for (int i = t; i < NBLK2; i += 256) s += partial[i];
    red[t] = s;
    __syncthreads();
#pragma unroll
    for (int off = 128; off > 0; off >>= 1) {
        if (t < off) red[t] += red[t + off];
        __syncthreads();
    }
    if (t == 0) nrm[0] = fmax(sqrt(red[0]), 1e-12);
}

// ---------------------------------------------------------------------------
// Per-node fp64 softmax((z/||z|| + g)/T) + top-8 threshold mask (round-2 exact)
// ---------------------------------------------------------------------------
__global__ __launch_bounds__(256) void k_mask(const float* __restrict__ z,
                                              const float* __restrict__ gumbel,
                                              const double* __restrict__ nrm,
                                              const int* __restrict__ temperature,
                                              float* __restrict__ out) {
    const int n = blockIdx.x * 256 + threadIdx.x;
    if (n >= N_NODES) return;
    const double inv_nv = 1.0 / nrm[0];
    const double invT = 1.0 / (double)temperature[0];
    const float4* z4 = (const float4*)(z + (size_t)n * 16);
    const float4* g4 = (const float4*)(gumbel + (size_t)n * 16);
    double tl[16], y[16];
#pragma unroll
    for (int q = 0; q < 4; ++q) {
        float4 zv = z4[q];
        float4 gv = g4[q];
        tl[q * 4 + 0] = ((double)zv.x * inv_nv + (double)gv.x) * invT;
        tl[q * 4 + 1] = ((double)zv.y * inv_nv + (double)gv.y) * invT;
        tl[q * 4 + 2] = ((double)zv.z * inv_nv + (double)gv.z) * invT;
        tl[q * 4 + 3] = ((double)zv.w * inv_nv + (double)gv.w) * invT;
    }
    double m = tl[0];
#pragma unroll
    for (int i = 1; i < 16; ++i) m = fmax(m, tl[i]);
    double s = 0.0;
#pragma unroll
    for (int i = 0; i < 16; ++i) { y[i] = exp(tl[i] - m); s += y[i]; }
    const double inv_s = 1.0 / s;
#pragma unroll
    for (int i = 0; i < 16; ++i) y[i] *= inv_s;
    double thre = y[0];
#pragma unroll
    for (int i = 0; i < 16; ++i) {
        int c = 0, q = 0;
#pragma unroll
        for (int j = 0; j < 16; ++j) {
            c += (y[j] > y[i]) ? 1 : 0;
            q += (y[j] == y[i]) ? 1 : 0;
        }
        if (c <= 7 && 7 < c + q) thre = y[i];
    }
    float4* o4 = (float4*)(out + (size_t)n * 16);
#pragma unroll
    for (int qq = 0; qq < 4; ++qq) {
        float4 ov;
        ov.x = ((y[qq * 4 + 0] - thre + 1e-12) > 0.0) ? (float)y[qq * 4 + 0] : 0.f;
        ov.y = ((y[qq * 4 + 1] - thre + 1e-12) > 0.0) ? (float)y[qq * 4 + 1] : 0.f;
        ov.z = ((y[qq * 4 + 2] - thre + 1e-12) > 0.0) ? (float)y[qq * 4 + 2] : 0.f;
        ov.w = ((y[qq * 4 + 3] - thre + 1e-12) > 0.0) ? (float)y[qq * 4 + 3] : 0.f;
        o4[qq] = ov;
    }
}

// ---------------------------------------------------------------------------
extern "C" void kernel_launch(void* const* d_in, const int* in_sizes, int n_in,
                              void* d_out, int out_size, void* d_ws, size_t ws_size,
                              hipStream_t stream) {
    const float* feat    = (const float*)d_in[0];   // [N,64]
    const float* values  = (const float*)d_in[1];   // [E]
    const float* w0      = (const float*)d_in[2];   // [64,129]
    const float* b0      = (const float*)d_in[3];   // [64]
    const float* w1      = (const float*)d_in[4];   // [1,64]
    const float* b1      = (const float*)d_in[5];   // [1]
    const float* gumbel  = (const float*)d_in[6];   // [E]
    const int*   indices = (const int*)d_in[7];     // [2,E]
    const int*   temp    = (const int*)d_in[9];     // scalar
    float* out = (float*)d_out;

    // workspace: w0T 32KB | AB 51.2MB | z 6.4MB | partial | nrm
    float*  w0T     = (float*)d_ws;
    float*  AB      = (float*)((char*)d_ws + 64 * 128 * 4);
    float*  zbuf    = (float*)((char*)d_ws + 64 * 128 * 4 + (size_t)N_NODES * 128 * 4);
    double* partial = (double*)((char*)d_ws + 64 * 128 * 4 + (size_t)N_NODES * 128 * 4
                                + (size_t)N_EDGES * 4);
    double* nrm     = partial + NBLK2;

    k_prep<<<32, 256, 0, stream>>>(w0, w0T);
    k_ab  <<<NBLK_AB, 256, 0, stream>>>(feat, w0T, b0, AB);
    k_edge<<<NBLK2, 256, 0, stream>>>(AB, values, indices, w0, w1, b1, zbuf, partial);
    k_norm<<<1, 256, 0, stream>>>(partial, nrm);
    k_mask<<<(N_NODES + 255) / 256, 256, 0, stream>>>(zbuf, gumbel, nrm, temp, out);
}